// Round 6
// baseline (52.775 us; speedup 1.0000x reference)
//
#include <hip/hip_runtime.h>
#include <math.h>

#define DD 4096
#define NP 32
#define BB 8
#define BT 128            // chain block threads
#define NBLK 32           // DD / BT blocks per batch

// ws layout (floats): Qws[B][32][32] = 8192 ; partial[B][32][NBLK] = 8192

// --- Kernel 1: per-batch register MGS (validated r2/r4/r5), Q -> ws ---
__global__ __launch_bounds__(64) void gs_kernel(const float* __restrict__ eig,
                                                const int* __restrict__ pos,
                                                float* __restrict__ Qws) {
    const int b = blockIdx.x;
    const int tid = threadIdx.x;
    const int r = tid & 31;
    __shared__ int ps[NP];
    if (tid < NP) ps[tid] = pos[b * NP + tid];
    __syncthreads();
    float a[NP];
    {
        const float4* arow = (const float4*)(eig + (size_t)ps[r] * DD);
#pragma unroll
        for (int i = 0; i < 8; i++) {
            float4 t = arow[i];
            a[4 * i] = t.x; a[4 * i + 1] = t.y; a[4 * i + 2] = t.z; a[4 * i + 3] = t.w;
        }
    }
    for (int k = 0; k < NP; k++) {
        float rk[NP];
#pragma unroll
        for (int i = 0; i < NP; i++) rk[i] = __shfl(a[i], k);   // broadcast row k
        float n0 = 0.f, n1 = 0.f;
#pragma unroll
        for (int i = 0; i < NP; i += 2) { n0 += rk[i] * rk[i]; n1 += rk[i + 1] * rk[i + 1]; }
        float inv = 1.0f / sqrtf(n0 + n1);
#pragma unroll
        for (int i = 0; i < NP; i++) rk[i] *= inv;
        float d0 = 0.f, d1 = 0.f;
#pragma unroll
        for (int i = 0; i < NP; i += 2) { d0 += a[i] * rk[i]; d1 += a[i + 1] * rk[i + 1]; }
        float f = (r > k) ? (d0 + d1) : 0.f;
#pragma unroll
        for (int i = 0; i < NP; i++) a[i] = (r == k) ? rk[i] : (a[i] - f * rk[i]);
    }
    if (tid < NP) {
        float4* q = (float4*)(Qws + ((size_t)b * NP + r) * NP);
#pragma unroll
        for (int i = 0; i < 8; i++)
            q[i] = make_float4(a[4 * i], a[4 * i + 1], a[4 * i + 2], a[4 * i + 3]);
    }
}

// --- Kernel 2: per-(b,d) chain. pos/Q via uniform scalar loads; LDS only for wsum ---
__global__ __launch_bounds__(BT, 1) void chain_kernel(const float* __restrict__ eig,
                                                      const float* __restrict__ v,
                                                      const int* __restrict__ pos,
                                                      const float* __restrict__ Qws,
                                                      float* __restrict__ out,
                                                      float* __restrict__ partial) {
    const int b = blockIdx.y;
    const int tid = threadIdx.x;
    const int d = blockIdx.x * BT + tid;
    const int lane = tid & 63;
    const int wid = tid >> 6;
    __shared__ float wsum[BT / 64][NP];

    // p row: 128B contiguous per thread (L2/L3-warm across batches)
    float p[NP];
    {
        const float4* prow = (const float4*)(eig + (size_t)d * DD);
#pragma unroll
        for (int i = 0; i < 8; i++) {
            float4 t4 = prow[i];
            p[4 * i] = t4.x; p[4 * i + 1] = t4.y; p[4 * i + 2] = t4.z; p[4 * i + 3] = t4.w;
        }
    }

    // v gather: pos[] is block-uniform -> s_load; v loads coalesced per k
    float vv[NP];
#pragma unroll
    for (int k = 0; k < NP; k++) {
        int pk = pos[b * NP + k];               // uniform -> SGPR
        vv[k] = v[(size_t)pk * DD + d];
    }
    float e[NP];
    {
        float s = 0.f;
#pragma unroll
        for (int k = 0; k < NP; k++) { e[k] = expf(-0.5f * s); s += vv[k]; }
    }

    float diagU = 0.f;
#pragma unroll
    for (int j = 0; j < NP; j++) diagU += p[j] * p[j];

    // 32 dots t_k = q_k . p  -- Q is block-uniform: scalar loads, no LDS, no barrier
    const float* Qb = Qws + (size_t)b * NP * NP;
    float t[NP];
#pragma unroll
    for (int k = 0; k < NP; k++) {
        float a0 = 0.f, a1 = 0.f;
#pragma unroll
        for (int i = 0; i < NP; i += 2) {
            a0 += Qb[k * NP + i]     * p[i];
            a1 += Qb[k * NP + i + 1] * p[i + 1];
        }
        t[k] = a0 + a1;
    }

    // prefix chain: 1 FMA/step
    float pr[NP];
    float un = diagU;
#pragma unroll
    for (int k = 0; k < NP; k++) {
        pr[k] = fabsf(un) * (1.0f / (NP - k)) * e[k];
        un -= t[k] * t[k];
    }
    // coalesced stores per k-plane
#pragma unroll
    for (int k = 0; k < NP; k++) out[((size_t)(b * NP + k)) * DD + d] = pr[k];
    // 32 independent wave reductions (deterministic)
#pragma unroll
    for (int k = 0; k < NP; k++) {
        float red = pr[k];
        red += __shfl_xor(red, 1);  red += __shfl_xor(red, 2);  red += __shfl_xor(red, 4);
        red += __shfl_xor(red, 8);  red += __shfl_xor(red, 16); red += __shfl_xor(red, 32);
        if (lane == 0) wsum[wid][k] = red;
    }
    __syncthreads();
    if (tid < NP)
        partial[((size_t)(b * NP + tid)) * NBLK + blockIdx.x] = wsum[0][tid] + wsum[1][tid];
}

// --- Kernel 3: deterministic normalization, lane-parallel sum ---
__global__ __launch_bounds__(256) void norm_kernel(float* __restrict__ out,
                                                   const float* __restrict__ partial) {
    const int bk = blockIdx.x;  // 0..B*NP-1
    __shared__ float invs;
    if (threadIdx.x < 64) {
        float s = (threadIdx.x < NBLK) ? partial[(size_t)bk * NBLK + threadIdx.x] : 0.f;
        s += __shfl_xor(s, 1);  s += __shfl_xor(s, 2);  s += __shfl_xor(s, 4);
        s += __shfl_xor(s, 8);  s += __shfl_xor(s, 16); s += __shfl_xor(s, 32);
        if (threadIdx.x == 0) invs = 1.0f / s;
    }
    __syncthreads();
    const float iv = invs;
    float4* o = (float4*)(out + (size_t)bk * DD);
#pragma unroll
    for (int i = threadIdx.x; i < DD / 4; i += 256) {
        float4 x = o[i];
        x.x *= iv; x.y *= iv; x.z *= iv; x.w *= iv;
        o[i] = x;
    }
}

extern "C" void kernel_launch(void* const* d_in, const int* in_sizes, int n_in,
                              void* d_out, int out_size, void* d_ws, size_t ws_size,
                              hipStream_t stream) {
    const float* eig = (const float*)d_in[0];   // (4096,4096) f32
    const float* v   = (const float*)d_in[1];   // (4096,4096) f32, symmetric
    const int*  pos  = (const int*)d_in[2];     // (8,32) i32
    float* out = (float*)d_out;                 // (8,32,4096) f32
    float* ws  = (float*)d_ws;
    float* Qws     = ws;                        // 8*32*32
    float* partial = Qws + BB * NP * NP;        // 8*32*NBLK

    gs_kernel<<<dim3(BB), 64, 0, stream>>>(eig, pos, Qws);
    chain_kernel<<<dim3(NBLK, BB), BT, 0, stream>>>(eig, v, pos, Qws, out, partial);
    norm_kernel<<<dim3(BB * NP), 256, 0, stream>>>(out, partial);
}

// Round 7
// 42.015 us; speedup vs baseline: 1.2561x; 1.2561x over previous
//
#include <hip/hip_runtime.h>
#include <math.h>

#define DD 4096
#define NP 32
#define BB 8
#define BT 128            // chain block threads
#define NBLK 32           // DD / BT blocks per batch

// ws layout (floats): Qws[B][32][32] = 8192 ; partial[B][32][NBLK] = 8192

// --- Kernel 1: per-batch register MGS (validated r2/r4/r5), Q -> ws ---
__global__ __launch_bounds__(64) void gs_kernel(const float* __restrict__ eig,
                                                const int* __restrict__ pos,
                                                float* __restrict__ Qws) {
    const int b = blockIdx.x;
    const int tid = threadIdx.x;
    const int r = tid & 31;
    __shared__ int ps[NP];
    if (tid < NP) ps[tid] = pos[b * NP + tid];
    __syncthreads();
    float a[NP];
    {
        const float4* arow = (const float4*)(eig + (size_t)ps[r] * DD);
#pragma unroll
        for (int i = 0; i < 8; i++) {
            float4 t = arow[i];
            a[4 * i] = t.x; a[4 * i + 1] = t.y; a[4 * i + 2] = t.z; a[4 * i + 3] = t.w;
        }
    }
    for (int k = 0; k < NP; k++) {
        float rk[NP];
#pragma unroll
        for (int i = 0; i < NP; i++) rk[i] = __shfl(a[i], k);   // broadcast row k
        float n0 = 0.f, n1 = 0.f;
#pragma unroll
        for (int i = 0; i < NP; i += 2) { n0 += rk[i] * rk[i]; n1 += rk[i + 1] * rk[i + 1]; }
        float inv = 1.0f / sqrtf(n0 + n1);
#pragma unroll
        for (int i = 0; i < NP; i++) rk[i] *= inv;
        float d0 = 0.f, d1 = 0.f;
#pragma unroll
        for (int i = 0; i < NP; i += 2) { d0 += a[i] * rk[i]; d1 += a[i + 1] * rk[i + 1]; }
        float f = (r > k) ? (d0 + d1) : 0.f;
#pragma unroll
        for (int i = 0; i < NP; i++) a[i] = (r == k) ? rk[i] : (a[i] - f * rk[i]);
    }
    if (tid < NP) {
        float4* q = (float4*)(Qws + ((size_t)b * NP + r) * NP);
#pragma unroll
        for (int i = 0; i < 8; i++)
            q[i] = make_float4(a[4 * i], a[4 * i + 1], a[4 * i + 2], a[4 * i + 3]);
    }
}

// --- Kernel 2: per-(b,d) chain, phase-separated (dots -> prefix -> stores -> reduces).
//     Q staged in LDS (R6 showed global broadcast reads cost +11 us). ---
__global__ __launch_bounds__(BT, 1) void chain_kernel(const float* __restrict__ eig,
                                                      const float* __restrict__ v,
                                                      const int* __restrict__ pos,
                                                      const float* __restrict__ Qws,
                                                      float* __restrict__ out,
                                                      float* __restrict__ partial) {
    const int b = blockIdx.y;
    const int tid = threadIdx.x;
    const int d = blockIdx.x * BT + tid;
    const int lane = tid & 63;
    const int wid = tid >> 6;
    __shared__ float Q[NP][NP];
    __shared__ int ps[NP];
    __shared__ float wsum[BT / 64][NP];
    if (tid < NP) ps[tid] = pos[b * NP + tid];
    {   // Q: 1024 floats = 256 float4, 128 threads x2
        const float4* src = (const float4*)(Qws + (size_t)b * NP * NP);
        float4* dst = (float4*)&Q[0][0];
        dst[tid] = src[tid];
        dst[tid + BT] = src[tid + BT];
    }
    __syncthreads();

    float p[NP];
    {
        const float4* prow = (const float4*)(eig + (size_t)d * DD);
#pragma unroll
        for (int i = 0; i < 8; i++) {
            float4 t4 = prow[i];
            p[4 * i] = t4.x; p[4 * i + 1] = t4.y; p[4 * i + 2] = t4.z; p[4 * i + 3] = t4.w;
        }
    }
    float vv[NP];
#pragma unroll
    for (int k = 0; k < NP; k++) vv[k] = v[(size_t)ps[k] * DD + d];
    float e[NP];
    {
        float s = 0.f;
#pragma unroll
        for (int k = 0; k < NP; k++) { e[k] = expf(-0.5f * s); s += vv[k]; }
    }
    float diagU = 0.f;
#pragma unroll
    for (int j = 0; j < NP; j++) diagU += p[j] * p[j];

    // ---- all 32 dots, independent (broadcast LDS reads, deep ILP) ----
    float t[NP];
#pragma unroll
    for (int k = 0; k < NP; k++) {
        const float4* q4 = (const float4*)&Q[k][0];
        float a0 = 0.f, a1 = 0.f;
#pragma unroll
        for (int i = 0; i < 8; i += 2) {
            float4 qa = q4[i], qb = q4[i + 1];
            a0 += qa.x * p[4 * i]     + qa.y * p[4 * i + 1] + qa.z * p[4 * i + 2] + qa.w * p[4 * i + 3];
            a1 += qb.x * p[4 * i + 4] + qb.y * p[4 * i + 5] + qb.z * p[4 * i + 6] + qb.w * p[4 * i + 7];
        }
        t[k] = a0 + a1;
    }
    // ---- prefix chain: 1 FMA/step ----
    float pr[NP];
    float un = diagU;
#pragma unroll
    for (int k = 0; k < NP; k++) {
        pr[k] = fabsf(un) * (1.0f / (NP - k)) * e[k];
        un -= t[k] * t[k];
    }
    // ---- stores (coalesced 4B/lane per k-plane) ----
#pragma unroll
    for (int k = 0; k < NP; k++) out[((size_t)(b * NP + k)) * DD + d] = pr[k];
    // ---- 32 independent wave reductions, pipelined ----
#pragma unroll
    for (int k = 0; k < NP; k++) {
        float red = pr[k];
        red += __shfl_xor(red, 1);  red += __shfl_xor(red, 2);  red += __shfl_xor(red, 4);
        red += __shfl_xor(red, 8);  red += __shfl_xor(red, 16); red += __shfl_xor(red, 32);
        if (lane == 0) wsum[wid][k] = red;
    }
    __syncthreads();
    if (tid < NP)
        partial[((size_t)(b * NP + tid)) * NBLK + blockIdx.x] = wsum[0][tid] + wsum[1][tid];
}

// --- Kernel 3: deterministic normalization, lane-parallel sum ---
__global__ __launch_bounds__(256) void norm_kernel(float* __restrict__ out,
                                                   const float* __restrict__ partial) {
    const int bk = blockIdx.x;  // 0..B*NP-1
    __shared__ float invs;
    if (threadIdx.x < 64) {
        float s = (threadIdx.x < NBLK) ? partial[(size_t)bk * NBLK + threadIdx.x] : 0.f;
        s += __shfl_xor(s, 1);  s += __shfl_xor(s, 2);  s += __shfl_xor(s, 4);
        s += __shfl_xor(s, 8);  s += __shfl_xor(s, 16); s += __shfl_xor(s, 32);
        if (threadIdx.x == 0) invs = 1.0f / s;
    }
    __syncthreads();
    const float iv = invs;
    float4* o = (float4*)(out + (size_t)bk * DD);
#pragma unroll
    for (int i = threadIdx.x; i < DD / 4; i += 256) {
        float4 x = o[i];
        x.x *= iv; x.y *= iv; x.z *= iv; x.w *= iv;
        o[i] = x;
    }
}

extern "C" void kernel_launch(void* const* d_in, const int* in_sizes, int n_in,
                              void* d_out, int out_size, void* d_ws, size_t ws_size,
                              hipStream_t stream) {
    const float* eig = (const float*)d_in[0];   // (4096,4096) f32
    const float* v   = (const float*)d_in[1];   // (4096,4096) f32, symmetric
    const int*  pos  = (const int*)d_in[2];     // (8,32) i32
    float* out = (float*)d_out;                 // (8,32,4096) f32
    float* ws  = (float*)d_ws;
    float* Qws     = ws;                        // 8*32*32
    float* partial = Qws + BB * NP * NP;        // 8*32*NBLK

    gs_kernel<<<dim3(BB), 64, 0, stream>>>(eig, pos, Qws);
    chain_kernel<<<dim3(NBLK, BB), BT, 0, stream>>>(eig, v, pos, Qws, out, partial);
    norm_kernel<<<dim3(BB * NP), 256, 0, stream>>>(out, partial);
}